// Round 5
// baseline (711.560 us; speedup 1.0000x reference)
//
#include <hip/hip_runtime.h>

#define TT    512
#define BATCH 2048
#define DIN   64
#define HD    10
#define WROW  (DIN + HD)     // 74
#define NGATE 40             // 4 gates x 10 units
#define ZSTRIDE (BATCH * NGATE)                     // floats per t-slab
#define ZNEED ((size_t)(TT + 4) * ZSTRIDE * 4)      // bytes incl. 3-deep prefetch pad

// ---------------- Kernel 1: Z[t*B+b, n] = X[t,b,:] . W_n + bias_n ----------------
// Block = 256 threads; n = tid&63 (lanes of a wave = one x-row, broadcast LDS reads),
// 64 m-rows per block in 4 chunks of 16 (staged coalesced via float4).
__global__ __launch_bounds__(256, 2)
void zgemm_kernel(const float* __restrict__ X,
                  const float* __restrict__ Wf, const float* __restrict__ bf,
                  const float* __restrict__ Wi, const float* __restrict__ bi,
                  const float* __restrict__ Wu, const float* __restrict__ bu,
                  const float* __restrict__ Wo, const float* __restrict__ bo,
                  float* __restrict__ Z)
{
    const int tid  = threadIdx.x;
    const int n    = tid & 63;          // output column (only n<40 real)
    const int msub = tid >> 6;          // wave id 0..3
    __shared__ float xs[16][64];

    float w[DIN];
    float bias = 0.f;
    {
        const float* Wg = Wf; const float* bg = bf;
        const int g = n / HD;
        if (g == 1) { Wg = Wi; bg = bi; }
        else if (g == 2) { Wg = Wu; bg = bu; }
        else if (g == 3) { Wg = Wo; bg = bo; }
        const int q = n - g * HD;
        if (n < NGATE) {
            #pragma unroll
            for (int k = 0; k < DIN; ++k) w[k] = Wg[q * WROW + k];
            bias = bg[q];
        } else {
            #pragma unroll
            for (int k = 0; k < DIN; ++k) w[k] = 0.f;
        }
    }

    const size_t m0 = (size_t)blockIdx.x * 64;      // 64 rows per block
    #pragma unroll 1
    for (int c = 0; c < 4; ++c) {
        const size_t mc = m0 + (size_t)c * 16;
        __syncthreads();
        // stage 16 rows (1024 floats) coalesced: thread -> float4 at flat offset 4*tid
        {
            const float4 xv = *reinterpret_cast<const float4*>(&X[mc * DIN + (size_t)tid * 4]);
            *reinterpret_cast<float4*>(&xs[0][0] + tid * 4) = xv;
        }
        __syncthreads();
        #pragma unroll
        for (int j = 0; j < 4; ++j) {
            const int ml = msub * 4 + j;            // row within chunk (uniform per wave)
            float s0 = bias, s1 = 0.f, s2 = 0.f, s3 = 0.f;
            #pragma unroll
            for (int k = 0; k < DIN; k += 4) {
                float4 xq = *reinterpret_cast<const float4*>(&xs[ml][k]);  // broadcast
                s0 = fmaf(w[k + 0], xq.x, s0);
                s1 = fmaf(w[k + 1], xq.y, s1);
                s2 = fmaf(w[k + 2], xq.z, s2);
                s3 = fmaf(w[k + 3], xq.w, s3);
            }
            if (n < NGATE) Z[(mc + ml) * NGATE + n] = (s0 + s1) + (s2 + s3);
        }
    }
}

// ---------------- Kernel 2: recurrence only (no X, no LDS, no barriers) ----------------
// One wave per batch row. Lane = 16*g + v; active v in [6,15] owns unit uw = 15-v
// for the z/cos computation (reversed so flip(cumprod) = DPP row_shl suffix product);
// scan result for unit us = v-6 lands on the same lane.
__global__ __launch_bounds__(64, 2)
void qlstm_rec_kernel(const float* __restrict__ Z,
                      const float* __restrict__ Wf, const float* __restrict__ Wi,
                      const float* __restrict__ Wu, const float* __restrict__ Wo,
                      float* __restrict__ out)
{
    const int row  = blockIdx.x;
    const int lane = threadIdx.x;
    const int g    = lane >> 4;
    const int v    = lane & 15;
    const bool act_lane = (v >= 6);

    const float LOG2E  = 1.4426950408889634f;
    const float INV2PI = 0.15915494309189535f;

    float cmul = -LOG2E, amul = 1.f, aadd = 0.f;
    const float* Wg = Wf;
    if (g == 1) { Wg = Wi; }
    else if (g == 2) { Wg = Wu; cmul = -2.f * LOG2E; amul = 2.f; aadd = -1.f; }
    else if (g == 3) { Wg = Wo; }

    float wh[HD];
    if (act_lane) {
        const int uw = 15 - v;
        #pragma unroll
        for (int k = 0; k < HD; ++k) wh[k] = Wg[uw * WROW + DIN + k];
    } else {
        #pragma unroll
        for (int k = 0; k < HD; ++k) wh[k] = 0.f;
    }

    // per-lane Z column: n = g*10 + (15-v), clamped for dummy lanes (v<6)
    int n = g * HD + (15 - v);
    if (n > NGATE - 1) n = NGATE - 1;
    const float* Zp = Z + (size_t)row * NGATE + n;

    float h[HD];
    #pragma unroll
    for (int k = 0; k < HD; ++k) h[k] = 0.f;
    float c = 0.f;
    float hkeep = 0.f;

    // 3-deep Z prefetch (pad region past t=TT-1 is poison but finite & unused)
    float z0 = Zp[0];
    float z1 = Zp[(size_t)ZSTRIDE];
    float z2 = Zp[(size_t)2 * ZSTRIDE];

    #pragma unroll 1
    for (int t = 0; t < TT; ++t) {
        const float zx = z0;
        z0 = z1; z1 = z2;
        z2 = Zp[(size_t)(t + 3) * ZSTRIDE];

        // ---- recurrence chain ----
        float za = zx, zb = 0.f;
        #pragma unroll
        for (int j = 0; j < HD; j += 2) {
            za = fmaf(wh[j],     h[j],     za);
            zb = fmaf(wh[j + 1], h[j + 1], zb);
        }
        float z = za + zb;
        z = fminf(fmaxf(z, -5.f), 5.f);
        float p = __builtin_amdgcn_cosf(z * INV2PI);

        // suffix product within 16-lane row: p[v] = prod_{v'>=v} p[v']
        {
            int s_;
            s_ = __builtin_amdgcn_update_dpp(0x3f800000, __float_as_int(p), 0x101, 0xF, 0xF, false);
            p *= __int_as_float(s_);
            s_ = __builtin_amdgcn_update_dpp(0x3f800000, __float_as_int(p), 0x102, 0xF, 0xF, false);
            p *= __int_as_float(s_);
            s_ = __builtin_amdgcn_update_dpp(0x3f800000, __float_as_int(p), 0x104, 0xF, 0xF, false);
            p *= __int_as_float(s_);
            s_ = __builtin_amdgcn_update_dpp(0x3f800000, __float_as_int(p), 0x108, 0xF, 0xF, false);
            p *= __int_as_float(s_);
        }

        float e = __builtin_amdgcn_exp2f(cmul * p);
        float a = amul * __builtin_amdgcn_rcpf(1.f + e) + aadd;

        // gather the 4 gate values for this lane's unit (same v across groups)
        float fg = __shfl(a, v);
        float ig = __shfl(a, 16 + v);
        float ug = __shfl(a, 32 + v);
        float og = __shfl(a, 48 + v);

        c = fmaf(fg, c, ig * ug);
        float e2 = __builtin_amdgcn_exp2f(-2.f * LOG2E * c);
        float th = 2.f * __builtin_amdgcn_rcpf(1.f + e2) - 1.f;   // tanh(c)
        float hpre = og * th;
        float h9 = __int_as_float(__builtin_amdgcn_readlane(__float_as_int(hpre), 15)); // unit 9
        float m  = __builtin_amdgcn_cosf(h9 * INV2PI);
        float hnew = hpre * m;
        hkeep = hnew;

        if (lane >= 6 && lane < 16) out[((size_t)t * BATCH + row) * HD + (lane - 6)] = hnew;

        #pragma unroll
        for (int j = 0; j < HD; ++j)
            h[j] = __int_as_float(__builtin_amdgcn_readlane(__float_as_int(hnew), 6 + j));
    }

    if (lane >= 6 && lane < 16) {
        const size_t base = (size_t)TT * BATCH * HD;
        out[base + (size_t)row * HD + (lane - 6)] = hkeep;
        out[base + (size_t)BATCH * HD + (size_t)row * HD + (lane - 6)] = c;
    }
}

// ---------------- Fallback: R3 fused kernel (used only if ws too small) ----------------
__global__ __launch_bounds__(64, 2)
void qlstm_fused_kernel(const float* __restrict__ X,
                        const float* __restrict__ Wf, const float* __restrict__ bf,
                        const float* __restrict__ Wi, const float* __restrict__ bi,
                        const float* __restrict__ Wu, const float* __restrict__ bu,
                        const float* __restrict__ Wo, const float* __restrict__ bo,
                        float* __restrict__ out)
{
    const int row  = blockIdx.x;
    const int lane = threadIdx.x;
    const int g    = lane >> 4;
    const int v    = lane & 15;
    const bool act_lane = (v >= 6);

    __shared__ float xs[2][DIN];

    const float LOG2E  = 1.4426950408889634f;
    const float INV2PI = 0.15915494309189535f;

    float cmul = -LOG2E, amul = 1.f, aadd = 0.f;
    const float* Wg = Wf; const float* bg = bf;
    if (g == 1) { Wg = Wi; bg = bi; }
    else if (g == 2) { Wg = Wu; bg = bu; cmul = -2.f * LOG2E; amul = 2.f; aadd = -1.f; }
    else if (g == 3) { Wg = Wo; bg = bo; }

    float wx[DIN];
    float wh[HD];
    float bias = 0.f;
    if (act_lane) {
        const int uw = 15 - v;
        #pragma unroll
        for (int k = 0; k < DIN; ++k) wx[k] = Wg[uw * WROW + k];
        #pragma unroll
        for (int k = 0; k < HD; ++k)  wh[k] = Wg[uw * WROW + DIN + k];
        bias = bg[uw];
    } else {
        #pragma unroll
        for (int k = 0; k < DIN; ++k) wx[k] = 0.f;
        #pragma unroll
        for (int k = 0; k < HD; ++k)  wh[k] = 0.f;
    }

    float h[HD];
    #pragma unroll
    for (int k = 0; k < HD; ++k) h[k] = 0.f;
    float c = 0.f;
    float hkeep = 0.f;

    const size_t xstep = (size_t)BATCH * DIN;
    const size_t xbase = (size_t)row * DIN + lane;

    xs[0][lane] = X[xbase];
    float xr = X[xstep + xbase];

    float zx;
    {
        float s0 = bias, s1 = 0.f, s2 = 0.f, s3 = 0.f;
        #pragma unroll
        for (int k = 0; k < DIN; k += 4) {
            float4 xq = *reinterpret_cast<const float4*>(&xs[0][k]);
            s0 = fmaf(wx[k + 0], xq.x, s0);
            s1 = fmaf(wx[k + 1], xq.y, s1);
            s2 = fmaf(wx[k + 2], xq.z, s2);
            s3 = fmaf(wx[k + 3], xq.w, s3);
        }
        zx = (s0 + s1) + (s2 + s3);
    }

    int cur = 0;
    for (int t = 0; t < TT; ++t) {
        const int nxt = cur ^ 1;
        if (t + 1 < TT) xs[nxt][lane] = xr;
        if (t + 2 < TT) xr = X[(size_t)(t + 2) * xstep + xbase];

        float za = zx, zb = 0.f;
        #pragma unroll
        for (int j = 0; j < HD; j += 2) {
            za = fmaf(wh[j],     h[j],     za);
            zb = fmaf(wh[j + 1], h[j + 1], zb);
        }
        float z = za + zb;
        z = fminf(fmaxf(z, -5.f), 5.f);
        float p = __builtin_amdgcn_cosf(z * INV2PI);

        {
            int s_;
            s_ = __builtin_amdgcn_update_dpp(0x3f800000, __float_as_int(p), 0x101, 0xF, 0xF, false);
            p *= __int_as_float(s_);
            s_ = __builtin_amdgcn_update_dpp(0x3f800000, __float_as_int(p), 0x102, 0xF, 0xF, false);
            p *= __int_as_float(s_);
            s_ = __builtin_amdgcn_update_dpp(0x3f800000, __float_as_int(p), 0x104, 0xF, 0xF, false);
            p *= __int_as_float(s_);
            s_ = __builtin_amdgcn_update_dpp(0x3f800000, __float_as_int(p), 0x108, 0xF, 0xF, false);
            p *= __int_as_float(s_);
        }

        float e = __builtin_amdgcn_exp2f(cmul * p);
        float a = amul * __builtin_amdgcn_rcpf(1.f + e) + aadd;

        float fg = __shfl(a, v);
        float ig = __shfl(a, 16 + v);
        float ug = __shfl(a, 32 + v);
        float og = __shfl(a, 48 + v);

        c = fmaf(fg, c, ig * ug);
        float e2 = __builtin_amdgcn_exp2f(-2.f * LOG2E * c);
        float th = 2.f * __builtin_amdgcn_rcpf(1.f + e2) - 1.f;
        float hpre = og * th;
        float h9 = __int_as_float(__builtin_amdgcn_readlane(__float_as_int(hpre), 15));
        float m  = __builtin_amdgcn_cosf(h9 * INV2PI);
        float hnew = hpre * m;
        hkeep = hnew;

        if (lane >= 6 && lane < 16) out[((size_t)t * BATCH + row) * HD + (lane - 6)] = hnew;

        #pragma unroll
        for (int j = 0; j < HD; ++j)
            h[j] = __int_as_float(__builtin_amdgcn_readlane(__float_as_int(hnew), 6 + j));

        if (t + 1 < TT) {
            float s0 = bias, s1 = 0.f, s2 = 0.f, s3 = 0.f;
            const float* xp = xs[nxt];
            #pragma unroll
            for (int k = 0; k < DIN; k += 4) {
                float4 xq = *reinterpret_cast<const float4*>(&xp[k]);
                s0 = fmaf(wx[k + 0], xq.x, s0);
                s1 = fmaf(wx[k + 1], xq.y, s1);
                s2 = fmaf(wx[k + 2], xq.z, s2);
                s3 = fmaf(wx[k + 3], xq.w, s3);
            }
            zx = (s0 + s1) + (s2 + s3);
        }
        cur = nxt;
    }

    if (lane >= 6 && lane < 16) {
        const size_t base = (size_t)TT * BATCH * HD;
        out[base + (size_t)row * HD + (lane - 6)] = hkeep;
        out[base + (size_t)BATCH * HD + (size_t)row * HD + (lane - 6)] = c;
    }
}

extern "C" void kernel_launch(void* const* d_in, const int* in_sizes, int n_in,
                              void* d_out, int out_size, void* d_ws, size_t ws_size,
                              hipStream_t stream) {
    const float* X  = (const float*)d_in[0];
    const float* Wf = (const float*)d_in[1];
    const float* bf = (const float*)d_in[2];
    const float* Wi = (const float*)d_in[3];
    const float* bi = (const float*)d_in[4];
    const float* Wu = (const float*)d_in[5];
    const float* bu = (const float*)d_in[6];
    const float* Wo = (const float*)d_in[7];
    const float* bo = (const float*)d_in[8];
    float* out = (float*)d_out;

    if (ws_size >= ZNEED) {
        float* Zbuf = (float*)d_ws;
        zgemm_kernel<<<(TT * BATCH) / 64, 256, 0, stream>>>(
            X, Wf, bf, Wi, bi, Wu, bu, Wo, bo, Zbuf);
        qlstm_rec_kernel<<<BATCH, 64, 0, stream>>>(Zbuf, Wf, Wi, Wu, Wo, out);
    } else {
        qlstm_fused_kernel<<<BATCH, 64, 0, stream>>>(
            X, Wf, bf, Wi, bi, Wu, bu, Wo, bo, out);
    }
}